// Round 16
// baseline (396.794 us; speedup 1.0000x reference)
//
#include <hip/hip_runtime.h>

// NeuralMapCell — ROUND 16. r15 passed 373 us. Profile top-5 = harness d_ws
// 0xAA fills (465 MB, 70 us each) => d_ws is huge & usable; all our kernels
// < 70 us; conv1 ~ 50 us by delta-fit (LDS staging bank conflicts + in-loop
// k1 loads + 1M atomics). This round:
//  - ALL scratch moved to d_ws (no more d_out aliasing).
//  - conv1 v4: sm[pix*33+i] (conflict-free staging AND reads), no atomics —
//    8 per-chunk partials c1p[chunk][o][p], plain stores.
//  - conv2 v2: lanes=w coalesced, no-transpose LDS staging (c1 channel-major),
//    wave-uniform k2 float4 loads, staging folds the 8-chunk sum.
//  - r1p v2: float4 d1 loads (1KB/wave-instr on the 122 MB stream).
//  - fused r1red2 -> k_small, ctred -> k_final; zero_c1 kernel gone.
// 10 launches total.
//
// d_ws scratch (floats):
#define WOFF_C1P 0         // 8 x 131072 = 1048576  conv1 chunk partials
#define WOFF_C2  1048576   // 246016   conv2 out (64ch x 62x62)
#define WOFF_P1  1294592   // 119168   r1 partials (931 x 128)
#define WOFF_P2  1413760   // 1024     r1 stage-2 partials (8 x 128)
#define WOFF_PC  1414784   // 4096     ct partials (16 x 256)
#define WOFF_SC  1418880   // 4096     scores
#define WOFF_AT  1422976   // 4096     softmax
#define WOFF_RT  1427072   // 256
#define WOFF_QT  1427328   // 256
#define WOFF_ST  1427584   // 256
// end = 1427840 floats = 5.7 MB << d_ws (~465 MB per fill counter)

#define FLAT  238144      // 64*61*61
#define NB_R1 931

__device__ __forceinline__ int read_idx(const int* p) {
    unsigned int u = (unsigned int)*p;
    int ex = (int)((u >> 23) & 0xFF);
    int v;
    if (ex >= 118 && ex <= 140) {
        union { unsigned int i; float f; } c; c.i = u;
        v = (int)(c.f + 0.5f);
    } else {
        v = (int)u;
    }
    return v < 0 ? 0 : (v > 63 ? 63 : v);
}

// ---- conv1 v4 (cross-corr, SAME, 3x3, 256->32), partial over 32-ch chunks.
// grid (64, 8): bx = 8x8 spatial tile, by = chunk. 256 thr: 64 px x 4 og.
// LDS sm[pix*33 + i]: staging writes hit distinct banks (c4*4 spread),
// compute reads stride 33 -> 2 lanes/bank (free).
__global__ __launch_bounds__(256) void k_conv1(const float* __restrict__ mem,
                                               const float* __restrict__ k1,
                                               float* __restrict__ c1p) {
    __shared__ float sm[3300];              // 100 pix x 33
    int t = threadIdx.x;
    int th = (blockIdx.x >> 3) * 8;
    int tw = (blockIdx.x & 7) * 8;
    int chunk = blockIdx.y;
    for (int u = t; u < 800; u += 256) {
        int pix = u >> 3, c4 = u & 7;
        int hh = th - 1 + pix / 10;
        int ww = tw - 1 + pix % 10;
        float4 v = make_float4(0.f, 0.f, 0.f, 0.f);
        if ((unsigned)hh < 64u && (unsigned)ww < 64u)
            v = *(const float4*)(mem + (size_t)(hh * 64 + ww) * 256
                                     + chunk * 32 + c4 * 4);
        float* s = sm + pix * 33 + c4 * 4;
        s[0] = v.x; s[1] = v.y; s[2] = v.z; s[3] = v.w;
    }
    __syncthreads();
    int lh = (t & 63) >> 3, lw = t & 7, og = t >> 6;
    float acc[8];
    #pragma unroll
    for (int j = 0; j < 8; ++j) acc[j] = 0.f;
    for (int dh = 0; dh < 3; ++dh)
        for (int dw = 0; dw < 3; ++dw) {
            const float* sp = sm + ((lh + dh) * 10 + lw + dw) * 33;
            const float* kb = k1 + ((size_t)(dh * 3 + dw) * 256
                                    + chunk * 32) * 32 + og * 8;
            #pragma unroll 8
            for (int i = 0; i < 32; ++i) {
                float m = sp[i];
                const float4* kp = (const float4*)(kb + (size_t)i * 32);
                float4 ka = kp[0], kb4 = kp[1];
                acc[0] += m * ka.x;  acc[1] += m * ka.y;
                acc[2] += m * ka.z;  acc[3] += m * ka.w;
                acc[4] += m * kb4.x; acc[5] += m * kb4.y;
                acc[6] += m * kb4.z; acc[7] += m * kb4.w;
            }
        }
    int p = (th + lh) * 64 + tw + lw;
    float* cb = c1p + (size_t)chunk * 131072 + (size_t)(og * 8) * 4096 + p;
    #pragma unroll
    for (int j = 0; j < 8; ++j) cb[(size_t)j * 4096] = acc[j];
}

// ---- conv2 v2 (cross-corr, VALID, 3x3, 32->64): c2[o*3844 + h*62 + w]
// grid 62 (one h row). 256 thr: w = t&63 (62 active), og = t>>6 (16 o each).
// Stage rows h..h+2 x 64 w x 32 i, summing the 8 conv1 chunk-partials.
__global__ __launch_bounds__(256) void k_conv2(const float* __restrict__ c1p,
                                               const float* __restrict__ k2,
                                               float* __restrict__ c2) {
    __shared__ float sm[6400];              // [i][200], pix = dr*64 + w
    int t = threadIdx.x;
    int h = blockIdx.x;                     // 0..61
    for (int e = t; e < 6144; e += 256) {
        int i = e / 192, pr = e % 192;
        int dr = pr >> 6, w = pr & 63;
        size_t off = (size_t)i * 4096 + (h + dr) * 64 + w;
        float s = 0.f;
        #pragma unroll
        for (int c = 0; c < 8; ++c) s += c1p[(size_t)c * 131072 + off];
        sm[i * 200 + pr] = s;
    }
    __syncthreads();
    int w = t & 63, og = t >> 6;
    if (w >= 62) return;
    float acc[16];
    #pragma unroll
    for (int j = 0; j < 16; ++j) acc[j] = 0.f;
    for (int dh = 0; dh < 3; ++dh)
        for (int dw = 0; dw < 3; ++dw) {
            const float* sp = sm + dh * 64 + w + dw;
            const float* kb = k2 + (size_t)((dh * 3 + dw) * 32) * 64 + og * 16;
            #pragma unroll 4
            for (int i = 0; i < 32; ++i) {
                float m = sp[i * 200];
                const float4* kp = (const float4*)(kb + (size_t)i * 64);
                float4 a = kp[0], b = kp[1], c = kp[2], d = kp[3];
                acc[0]  += m * a.x; acc[1]  += m * a.y;
                acc[2]  += m * a.z; acc[3]  += m * a.w;
                acc[4]  += m * b.x; acc[5]  += m * b.y;
                acc[6]  += m * b.z; acc[7]  += m * b.w;
                acc[8]  += m * c.x; acc[9]  += m * c.y;
                acc[10] += m * c.z; acc[11] += m * c.w;
                acc[12] += m * d.x; acc[13] += m * d.y;
                acc[14] += m * d.z; acc[15] += m * d.w;
            }
        }
    #pragma unroll
    for (int j = 0; j < 16; ++j)
        c2[(size_t)(og * 16 + j) * 3844 + h * 62 + w] = acc[j];
}

// ---- pool + dense1 partials v2: float4 d1 loads. 256 thr: jf = t&31, fs = t>>5.
__global__ __launch_bounds__(256) void k_r1p(const float* __restrict__ c2,
                                             const float* __restrict__ d1,
                                             float* __restrict__ p1) {
    __shared__ float pl[256];
    __shared__ float red[1024];
    int t = threadIdx.x;
    int f0 = blockIdx.x * 256;
    int fmax = FLAT - f0; if (fmax > 256) fmax = 256;
    float pv = 0.f;
    if (t < fmax) {
        int f = f0 + t;
        int o = f / 3721;
        int r = f % 3721;
        int h = r / 61, w = r % 61;
        const float* b = c2 + o * 3844 + h * 62 + w;
        pv = 0.25f * (b[0] + b[1] + b[62] + b[63]);
    }
    pl[t] = pv;
    __syncthreads();
    int jf = t & 31, fs = t >> 5;
    float4 a4 = make_float4(0.f, 0.f, 0.f, 0.f);
    int fbeg = fs * 32;
    int fend = fbeg + 32; if (fend > fmax) fend = fmax;
    for (int f = fbeg; f < fend; ++f) {
        float p = pl[f];
        float4 dv = *(const float4*)(d1 + (size_t)(f0 + f) * 128 + jf * 4);
        a4.x += p * dv.x; a4.y += p * dv.y;
        a4.z += p * dv.z; a4.w += p * dv.w;
    }
    *(float4*)(red + t * 4) = a4;          // red[(fs*32+jf)*4 + k]
    __syncthreads();
    if (t < 128) {
        int jf2 = t >> 2, k = t & 3;
        float s = 0.f;
        #pragma unroll
        for (int fs2 = 0; fs2 < 8; ++fs2)
            s += red[(fs2 * 32 + jf2) * 4 + k];
        p1[blockIdx.x * 128 + t] = s;      // j == t
    }
}

// ---- r1 reduce stage 1 (8 blocks x 128)
__global__ __launch_bounds__(128) void k_r1red1(const float* __restrict__ p1,
                                                float* __restrict__ p2) {
    int j = threadIdx.x;
    int b0 = blockIdx.x * 117;
    int b1 = b0 + 117; if (b1 > NB_R1) b1 = NB_R1;
    float s = 0.f;
    for (int b = b0; b < b1; ++b) s += p1[b * 128 + j];
    p2[blockIdx.x * 128 + j] = s;
}

// ---- small: fuses r1 stage-2 reduce; r_t/s_t/q_t
__global__ __launch_bounds__(256) void k_small(const float* __restrict__ p2,
                                               const float* __restrict__ d2,
                                               const float* __restrict__ inp,
                                               const float* __restrict__ ck,
                                               const float* __restrict__ rec,
                                               float* __restrict__ rt,
                                               float* __restrict__ qt,
                                               float* __restrict__ st) {
    __shared__ float s_r1[128], s_in[128], s_rt[256];
    int t = threadIdx.x;
    if (t < 128) {
        float s = 0.f;
        #pragma unroll
        for (int b = 0; b < 8; ++b) s += p2[b * 128 + t];
        s_r1[t] = s;
        s_in[t] = inp[t];
    }
    __syncthreads();
    float a = 0.f;
    for (int j = 0; j < 128; ++j) a += s_r1[j] * d2[j * 256 + t];
    rt[t] = a; s_rt[t] = a;
    float sv = 0.f;
    for (int k = 0; k < 128; ++k) sv += s_in[k] * rec[k * 256 + t];
    st[t] = sv;
    __syncthreads();
    float q = 0.f;
    for (int k = 0; k < 128; ++k) q += s_in[k] * ck[k * 256 + t];
    for (int k = 0; k < 256; ++k) q += s_rt[k] * ck[(128 + k) * 256 + t];
    qt[t] = q;
}

// ---- scores (unchanged)
__global__ __launch_bounds__(256) void k_scores(const float* __restrict__ qt,
                                                const float* __restrict__ mem,
                                                float* __restrict__ scores) {
    __shared__ float q[256];
    int t = threadIdx.x;
    q[t] = qt[t];
    __syncthreads();
    int wave = t >> 6, lane = t & 63;
    int base = (blockIdx.x * 4 + wave) * 16;
    float qx = q[lane * 4], qy = q[lane * 4 + 1],
          qz = q[lane * 4 + 2], qw = q[lane * 4 + 3];
    for (int r = 0; r < 16; ++r) {
        int p = base + r;
        float4 m = *(const float4*)(mem + (size_t)p * 256 + lane * 4);
        float acc = m.x * qx + m.y * qy + m.z * qz + m.w * qw;
        for (int off = 32; off; off >>= 1) acc += __shfl_down(acc, off);
        if (lane == 0) scores[p] = acc;
    }
}

__global__ __launch_bounds__(256) void k_softmax(const float* __restrict__ scores,
                                                 float* __restrict__ at) {
    __shared__ float red[256];
    int t = threadIdx.x;
    float m = -1e30f;
    for (int i = t; i < 4096; i += 256) m = fmaxf(m, scores[i]);
    red[t] = m; __syncthreads();
    for (int s = 128; s; s >>= 1) { if (t < s) red[t] = fmaxf(red[t], red[t + s]); __syncthreads(); }
    float mx = red[0]; __syncthreads();
    float sum = 0.f;
    for (int i = t; i < 4096; i += 256) sum += expf(scores[i] - mx);
    red[t] = sum; __syncthreads();
    for (int s = 128; s; s >>= 1) { if (t < s) red[t] += red[t + s]; __syncthreads(); }
    float inv = 1.f / red[0];
    for (int i = t; i < 4096; i += 256) at[i] = expf(scores[i] - mx) * inv;
}

__global__ __launch_bounds__(256) void k_ctp(const float* __restrict__ at,
                                             const float* __restrict__ mem,
                                             float* __restrict__ pc) {
    __shared__ float a[256];
    int t = threadIdx.x;
    int p0 = blockIdx.x * 256;
    a[t] = at[p0 + t];
    __syncthreads();
    float acc = 0.f;
    for (int pp = 0; pp < 256; ++pp)
        acc += a[pp] * mem[(size_t)(p0 + pp) * 256 + t];
    pc[blockIdx.x * 256 + t] = acc;
}

// ---- final: fuses ct reduce; writes c_t, r_t, updated column
__global__ __launch_bounds__(256) void k_final(const float* __restrict__ rt,
                                               const float* __restrict__ st,
                                               const float* __restrict__ pc,
                                               const float* __restrict__ mem,
                                               const float* __restrict__ rec,
                                               const int* __restrict__ px,
                                               const int* __restrict__ py,
                                               float* __restrict__ out) {
    __shared__ float s_diff[256], red[256];
    int t = threadIdx.x;
    int x = read_idx(px), y = read_idx(py);
    int pxy = x * 64 + y;
    float ctv = 0.f;
    #pragma unroll
    for (int b = 0; b < 16; ++b) ctv += pc[b * 256 + t];
    float stv = st[t], rtv = rt[t];
    float memt = mem[(size_t)pxy * 256 + t];
    red[t] = stv * rtv; __syncthreads();
    for (int s = 128; s; s >>= 1) { if (t < s) red[t] += red[t + s]; __syncthreads(); }
    float gimp = red[0]; __syncthreads();
    red[t] = stv * ctv; __syncthreads();
    for (int s = 128; s; s >>= 1) { if (t < s) red[t] += red[t + s]; __syncthreads(); }
    float limp = red[0];
    s_diff[t] = memt - stv;
    __syncthreads();
    float d = 0.f;
    for (int k = 0; k < 256; ++k)
        d += s_diff[k] * rec[(128 + k) * 256 + t];
    float frac = limp / (limp + gimp);
    float nv = memt + frac * d;
    out[t] = ctv;
    out[256 + t] = rtv;
    out[512 + (size_t)t * 4096 + pxy] = nv;
}

// ---- transpose (unchanged): new_mem[u][p] = mem[p][u], skip pxy column
__global__ __launch_bounds__(256) void k_transpose(const float* __restrict__ mem,
                                                   const int* __restrict__ px,
                                                   const int* __restrict__ py,
                                                   float* __restrict__ outm) {
    __shared__ float tile[64][65];
    int t = threadIdx.x;
    int p0 = blockIdx.x * 64;
    int u0 = blockIdx.y * 64;
    int x = read_idx(px), y = read_idx(py);
    int pxy = x * 64 + y;
    int lane = t & 63, grp = t >> 6;
    for (int r = 0; r < 16; ++r) {
        int pr = grp + r * 4;
        tile[pr][lane] = mem[(size_t)(p0 + pr) * 256 + u0 + lane];
    }
    __syncthreads();
    for (int r = 0; r < 16; ++r) {
        int ur = grp + r * 4;
        if (p0 + lane != pxy)
            outm[(size_t)(u0 + ur) * 4096 + p0 + lane] = tile[lane][ur];
    }
}

extern "C" void kernel_launch(void* const* d_in, const int* in_sizes, int n_in,
                              void* d_out, int out_size, void* d_ws, size_t ws_size,
                              hipStream_t stream) {
    const float* inp = (const float*)d_in[0];
    const float* mem = (const float*)d_in[1];
    const float* k1  = (const float*)d_in[2];
    const float* k2  = (const float*)d_in[3];
    const float* d1  = (const float*)d_in[4];
    const float* d2  = (const float*)d_in[5];
    const float* ck  = (const float*)d_in[6];
    const float* rec = (const float*)d_in[7];
    const int* px = (const int*)d_in[8];
    const int* py = (const int*)d_in[9];
    float* out = (float*)d_out;
    float* ws = (float*)d_ws;

    k_conv1<<<dim3(64, 8), 256, 0, stream>>>(mem, k1, ws + WOFF_C1P);
    k_conv2<<<62, 256, 0, stream>>>(ws + WOFF_C1P, k2, ws + WOFF_C2);
    k_r1p<<<NB_R1, 256, 0, stream>>>(ws + WOFF_C2, d1, ws + WOFF_P1);
    k_r1red1<<<8, 128, 0, stream>>>(ws + WOFF_P1, ws + WOFF_P2);
    k_small<<<1, 256, 0, stream>>>(ws + WOFF_P2, d2, inp, ck, rec,
                                   ws + WOFF_RT, ws + WOFF_QT, ws + WOFF_ST);
    k_scores<<<64, 256, 0, stream>>>(ws + WOFF_QT, mem, ws + WOFF_SC);
    k_softmax<<<1, 256, 0, stream>>>(ws + WOFF_SC, ws + WOFF_AT);
    k_ctp<<<16, 256, 0, stream>>>(ws + WOFF_AT, mem, ws + WOFF_PC);
    k_final<<<1, 256, 0, stream>>>(ws + WOFF_RT, ws + WOFF_ST, ws + WOFF_PC,
                                   mem, rec, px, py, out);
    k_transpose<<<dim3(64, 4), 256, 0, stream>>>(mem, px, py, out + 512);
}